// Round 8
// baseline (108.637 us; speedup 1.0000x reference)
//
#include <hip/hip_runtime.h>
#include <math.h>

// Problem constants
#define NTOK 16384
#define DDIM 4096
#define NEXP 64
#define KTOP 4

// GEMM config
#define SPLITK 8
#define KPER (DDIM / SPLITK)   // 512 k per split
#define BK 32                  // k per chunk (one 16x16x32 MFMA k-step)
#define NCH (KPER / BK)        // 16 chunks
#define BMB 256                // tokens per block = 8 waves x 32 rows
#define PDEPTH 4               // register pipeline depth (rotating buffers)

typedef __attribute__((ext_vector_type(8))) short short8;
typedef __attribute__((ext_vector_type(4))) float f32x4;

// ws layout:
//   part [NTOK][SPLITK][NEXP] f32 = 32 MB
//   Whi  [NEXP][DDIM] ushort      = 512 KB
//   Wlo  [NEXP][DDIM] ushort      = 512 KB

__device__ __forceinline__ unsigned short f2bf_rtn(float x) {
    unsigned int b = __float_as_uint(x);
    return (unsigned short)((b + 0x7FFFu + ((b >> 16) & 1u)) >> 16);
}
__device__ __forceinline__ float bf2f(unsigned short h) {
    return __uint_as_float(((unsigned int)h) << 16);
}

__device__ __forceinline__ short8 mk8(unsigned int a, unsigned int b,
                                      unsigned int c, unsigned int d) {
    union { unsigned int u[4]; short8 s; } p;
    p.u[0] = a; p.u[1] = b; p.u[2] = c; p.u[3] = d;
    return p.s;
}

// ---------------- Kernel 1: split W into bf16 hi/lo (RTN), zero counts -------
__global__ __launch_bounds__(256) void prep_kernel(
    const float* __restrict__ W, unsigned short* __restrict__ Whi,
    unsigned short* __restrict__ Wlo, float* __restrict__ counts)
{
    int idx = blockIdx.x * 256 + threadIdx.x;   // 0 .. 64*4096
    float x = W[idx];
    unsigned short h = f2bf_rtn(x);
    float lo = x - bf2f(h);
    Whi[idx] = h;
    Wlo[idx] = f2bf_rtn(lo);
    if (blockIdx.x == 0 && threadIdx.x < NEXP) counts[threadIdx.x] = 0.0f;
}

// ---------------- Kernel 2: bf16x3-split MFMA GEMM, W-slice in LDS -----------
// 512 blocks x 512 threads (8 waves), 1 resident block/CU (128 KB LDS).
// Block = 256 tokens x 64 experts x KPER k.  X read exactly once device-wide.
// A pipeline: EXPLICIT depth-4 rotating register buffers (xq[c&3], static
// indices under full unroll) -> fits VGPR budget, compiler keeps loads hoisted
// ~3 chunk-times (~1000 cyc) ahead of use. RTZ hi/lo split, swizzled LDS B.
__global__ __launch_bounds__(512, 2) void gemm_kernel(
    const float* __restrict__ X, const unsigned short* __restrict__ Whi,
    const unsigned short* __restrict__ Wlo, float* __restrict__ part)
{
    __shared__ unsigned short sHi[NEXP * KPER];   // 64 KB
    __shared__ unsigned short sLo[NEXP * KPER];   // 64 KB

    const int tid  = threadIdx.x;
    const int lane = tid & 63;
    const int w    = tid >> 6;                 // wave 0..7
    const int tb   = blockIdx.x >> 3;          // token block 0..63
    const int s    = blockIdx.x & 7;           // k-split    0..7
    const int kbase = s * KPER;
    const int tok0 = tb * BMB + w * 32;        // this wave's first row

    const int fr = lane & 15;                  // fragment row (token) / col (expert)
    const int fg = lane >> 4;                  // k subgroup 0..3
    const int kx = (fg * 8) ^ ((fr & 7) * 8);  // swizzled per-lane k offset (shorts)

    // A bases: row tok0 + mg*16 + fr, k = kbase + c*32 + fg*8 (imm offsets per c)
    const float* __restrict__ xa0 = X + (size_t)(tok0 + fr) * DDIM + kbase + fg * 8;
    const float* __restrict__ xa1 = xa0 + (size_t)16 * DDIM;

    // ---- stage W slice: thread t covers expert e=t>>3, pieces j=t&7 (+64i) --
    {
        const int e = tid >> 3;
        const int j = tid & 7;
        const unsigned short* gh = Whi + (size_t)e * DDIM + kbase + j * 8;
        const unsigned short* gl = Wlo + (size_t)e * DDIM + kbase + j * 8;
        const int m = (e & 7) * 8;             // XOR swizzle (ushort units)
        #pragma unroll
        for (int i = 0; i < 8; ++i) {
            const int kk = j * 8 + i * 64;
            short8 vh = *(const short8*)(gh + i * 64);
            short8 vl = *(const short8*)(gl + i * 64);
            *(short8*)&sHi[e * KPER + (kk ^ m)] = vh;
            *(short8*)&sLo[e * KPER + (kk ^ m)] = vl;
        }
    }

    // ---- explicit depth-4 rotating A-pipeline (64 VGPRs, static indices) ----
    float4 xq[PDEPTH][2][2];

#define LOADA(buf, c)                                                       \
    {                                                                       \
        xq[buf][0][0] = *(const float4*)(xa0 + (c) * BK);                   \
        xq[buf][0][1] = *(const float4*)(xa0 + (c) * BK + 4);               \
        xq[buf][1][0] = *(const float4*)(xa1 + (c) * BK);                   \
        xq[buf][1][1] = *(const float4*)(xa1 + (c) * BK + 4);               \
    }

    // fill the pipeline before the barrier (overlaps W staging)
    LOADA(0, 0)
    LOADA(1, 1)
    LOADA(2, 2)
    LOADA(3, 3)

    __syncthreads();

    f32x4 acc[2][4];
    #pragma unroll
    for (int mg = 0; mg < 2; ++mg)
        #pragma unroll
        for (int ng = 0; ng < 4; ++ng)
            acc[mg][ng] = (f32x4){0.f, 0.f, 0.f, 0.f};

    #pragma unroll
    for (int c = 0; c < NCH; ++c) {
        const int buf = c & (PDEPTH - 1);      // static under full unroll

        // ---- RTZ split A fp32 -> bf16 hi/lo fragments (consumes xq[buf]) ----
        short8 ahi[2], alo[2];
        #pragma unroll
        for (int mg = 0; mg < 2; ++mg) {
            unsigned int hi[4], lo[4];
            #pragma unroll
            for (int h = 0; h < 2; ++h) {
                const float4 q = xq[buf][mg][h];
                const unsigned int ux = __float_as_uint(q.x);
                const unsigned int uy = __float_as_uint(q.y);
                const unsigned int uz = __float_as_uint(q.z);
                const unsigned int uw = __float_as_uint(q.w);
                hi[h * 2]     = (ux >> 16) | (uy & 0xFFFF0000u);
                hi[h * 2 + 1] = (uz >> 16) | (uw & 0xFFFF0000u);
                const float lx = q.x - __uint_as_float(ux & 0xFFFF0000u);
                const float ly = q.y - __uint_as_float(uy & 0xFFFF0000u);
                const float lz = q.z - __uint_as_float(uz & 0xFFFF0000u);
                const float lw = q.w - __uint_as_float(uw & 0xFFFF0000u);
                lo[h * 2]     = (__float_as_uint(lx) >> 16) | (__float_as_uint(ly) & 0xFFFF0000u);
                lo[h * 2 + 1] = (__float_as_uint(lz) >> 16) | (__float_as_uint(lw) & 0xFFFF0000u);
            }
            ahi[mg] = mk8(hi[0], hi[1], hi[2], hi[3]);
            alo[mg] = mk8(lo[0], lo[1], lo[2], lo[3]);
        }

        // ---- refill the just-consumed buffer with chunk c+4 ----
        if (c + PDEPTH < NCH) LOADA(buf, c + PDEPTH)

        // ---- B from LDS (swizzled broadcast) + 24 MFMAs ----
        #pragma unroll
        for (int ng = 0; ng < 4; ++ng) {
            const int bE = (ng * 16 + fr) * KPER;
            const int t  = (c * BK) ^ kx;      // c*BK compile-time under unroll
            const short8 bh = *(const short8*)(sHi + bE + t);
            const short8 bl = *(const short8*)(sLo + bE + t);
            #pragma unroll
            for (int mg = 0; mg < 2; ++mg) {
                acc[mg][ng] = __builtin_amdgcn_mfma_f32_16x16x32_bf16(
                    ahi[mg], bh, acc[mg][ng], 0, 0, 0);
                acc[mg][ng] = __builtin_amdgcn_mfma_f32_16x16x32_bf16(
                    ahi[mg], bl, acc[mg][ng], 0, 0, 0);
                acc[mg][ng] = __builtin_amdgcn_mfma_f32_16x16x32_bf16(
                    alo[mg], bh, acc[mg][ng], 0, 0, 0);
            }
        }
    }
#undef LOADA

    // ---- store partials [n][s][e] (route reads 2 KB contiguous per token) ---
    // C/D layout: col = lane&15 (expert), row = fg*4 + reg (token)
    #pragma unroll
    for (int mg = 0; mg < 2; ++mg)
        #pragma unroll
        for (int r = 0; r < 4; ++r) {
            const int row = tok0 + mg * 16 + fg * 4 + r;
            float* __restrict__ pp = part + ((size_t)row * SPLITK + s) * NEXP;
            #pragma unroll
            for (int ng = 0; ng < 4; ++ng)
                pp[ng * 16 + fr] = acc[mg][ng][r];
        }
}

// ---------------- Kernel 3: softmax + group-limited top-k routing ------------
__global__ __launch_bounds__(256) void route_kernel(
    const float* __restrict__ part, float* __restrict__ outW,
    float* __restrict__ outI, float* __restrict__ counts)
{
    __shared__ int hist[NEXP];
    const int tid = threadIdx.x;
    if (tid < NEXP) hist[tid] = 0;
    __syncthreads();

    const int lane = tid & 63;
    const int wv   = tid >> 6;   // wave 0..3
    const int tok_base = blockIdx.x * 32 + wv * 8;

    for (int t = 0; t < 8; ++t) {
        const int n = tok_base + t;
        // sum split-K partials (layout [n][s][e]): 2 KB contiguous per token
        float L = 0.0f;
        #pragma unroll
        for (int s = 0; s < SPLITK; ++s)
            L += part[((size_t)n * SPLITK + s) * NEXP + lane];

        // softmax over 64 experts (wave = expert axis)
        float m = L;
        #pragma unroll
        for (int off = 32; off > 0; off >>= 1) m = fmaxf(m, __shfl_xor(m, off));
        float p = expf(L - m);
        float ssum = p;
        #pragma unroll
        for (int off = 32; off > 0; off >>= 1) ssum += __shfl_xor(ssum, off);
        float score = p / ssum;

        // group max within each 8-lane group
        float gm = score;
        gm = fmaxf(gm, __shfl_xor(gm, 1));
        gm = fmaxf(gm, __shfl_xor(gm, 2));
        gm = fmaxf(gm, __shfl_xor(gm, 4));

        // gather all 8 group maxima, serial top-4 groups (ties -> lower index)
        float ga[8];
        #pragma unroll
        for (int g = 0; g < 8; ++g) ga[g] = __shfl(gm, g * 8);
        unsigned selmask = 0u;
        #pragma unroll
        for (int r = 0; r < 4; ++r) {
            float best = -INFINITY; int bg = 0;
            #pragma unroll
            for (int g = 0; g < 8; ++g) {
                bool taken  = (selmask >> g) & 1u;
                bool better = (!taken) && (ga[g] > best);
                bg   = better ? g : bg;
                best = better ? ga[g] : best;
            }
            selmask |= (1u << bg);
        }

        // mask non-selected groups, wave-wide top-4 (ties -> lower idx)
        float ms = ((selmask >> (lane >> 3)) & 1u) ? score : -INFINITY;
        float wk[4]; int wi[4];
        #pragma unroll
        for (int r = 0; r < 4; ++r) {
            float v = ms; int ix = lane;
            #pragma unroll
            for (int off = 32; off > 0; off >>= 1) {
                float vo = __shfl_xor(v, off);
                int   io = __shfl_xor(ix, off);
                if (vo > v || (vo == v && io < ix)) { v = vo; ix = io; }
            }
            wk[r] = v; wi[r] = ix;
            if (lane == ix) ms = -INFINITY;
        }

        if (lane == 0) {
            *(float4*)&outW[(size_t)n * 4] = make_float4(wk[0], wk[1], wk[2], wk[3]);
            *(float4*)&outI[(size_t)n * 4] =
                make_float4((float)wi[0], (float)wi[1], (float)wi[2], (float)wi[3]);
            atomicAdd(&hist[wi[0]], 1);
            atomicAdd(&hist[wi[1]], 1);
            atomicAdd(&hist[wi[2]], 1);
            atomicAdd(&hist[wi[3]], 1);
        }
    }

    __syncthreads();
    if (tid < NEXP) atomicAdd(&counts[tid], (float)hist[tid]);
}

extern "C" void kernel_launch(void* const* d_in, const int* in_sizes, int n_in,
                              void* d_out, int out_size, void* d_ws, size_t ws_size,
                              hipStream_t stream) {
    const float* X = (const float*)d_in[0];
    const float* W = (const float*)d_in[1];

    float* outW   = (float*)d_out;                    // [N,4] weights
    float* outI   = outW + (size_t)NTOK * KTOP;       // [N,4] indices (as float)
    float* counts = outW + (size_t)2 * NTOK * KTOP;   // [64]  counts  (as float)

    float*          part = (float*)d_ws;                              // 32 MB
    unsigned short* Whi  = (unsigned short*)(part + (size_t)NTOK * SPLITK * NEXP);
    unsigned short* Wlo  = Whi + (size_t)NEXP * DDIM;

    prep_kernel<<<(NEXP * DDIM) / 256, 256, 0, stream>>>(W, Whi, Wlo, counts);
    gemm_kernel<<<(NTOK / BMB) * SPLITK, 512, 0, stream>>>(X, Whi, Wlo, part);
    route_kernel<<<NTOK / 32, 256, 0, stream>>>(part, outW, outI, counts);
}

// Round 9
// 101.283 us; speedup vs baseline: 1.0726x; 1.0726x over previous
//
#include <hip/hip_runtime.h>
#include <math.h>

// Problem constants
#define NTOK 16384
#define DDIM 4096
#define NEXP 64
#define KTOP 4

// GEMM config
#define SPLITK 8
#define KPER (DDIM / SPLITK)   // 512 k per split
#define BK 32                  // k per pipeline stage (one 16x16x32 MFMA k-step)
#define NSTG (KPER / BK)       // 16 stages
#define BMB 256                // tokens per block = 8 waves x 32 rows

typedef __attribute__((ext_vector_type(8))) short short8;
typedef __attribute__((ext_vector_type(4))) float f32x4;

// ws layout:
//   part [NTOK][SPLITK][NEXP] f32 = 32 MB
//   Whi  [NEXP][DDIM] ushort      = 512 KB
//   Wlo  [NEXP][DDIM] ushort      = 512 KB

__device__ __forceinline__ unsigned short f2bf_rtn(float x) {
    unsigned int b = __float_as_uint(x);
    return (unsigned short)((b + 0x7FFFu + ((b >> 16) & 1u)) >> 16);
}
__device__ __forceinline__ float bf2f(unsigned short h) {
    return __uint_as_float(((unsigned int)h) << 16);
}
__device__ __forceinline__ short8 mk8(unsigned int a, unsigned int b,
                                      unsigned int c, unsigned int d) {
    union { unsigned int u[4]; short8 s; } p;
    p.u[0] = a; p.u[1] = b; p.u[2] = c; p.u[3] = d;
    return p.s;
}
// async global->LDS, 16 B per lane; LDS dest = wave-uniform base + lane*16
__device__ __forceinline__ void gl2lds16(const void* g, void* l) {
    __builtin_amdgcn_global_load_lds(
        (const __attribute__((address_space(1))) unsigned int*)g,
        (__attribute__((address_space(3))) unsigned int*)l, 16, 0, 0);
}

// ---------------- Kernel 1: split W into bf16 hi/lo (RTN), zero counts -------
__global__ __launch_bounds__(256) void prep_kernel(
    const float* __restrict__ W, unsigned short* __restrict__ Whi,
    unsigned short* __restrict__ Wlo, float* __restrict__ counts)
{
    int idx = blockIdx.x * 256 + threadIdx.x;   // 0 .. 64*4096
    float x = W[idx];
    unsigned short h = f2bf_rtn(x);
    float lo = x - bf2f(h);
    Whi[idx] = h;
    Wlo[idx] = f2bf_rtn(lo);
    if (blockIdx.x == 0 && threadIdx.x < NEXP) counts[threadIdx.x] = 0.0f;
}

// ---------------- Kernel 2: bf16x3-split MFMA GEMM, global_load_lds pipeline -
// 512 blocks x 512 threads (8 waves), LDS 80 KB -> 2 blocks/CU, single round.
// 2-phase m97 template: issue stage t+1 (gload_lds, pre-swizzled per-lane
// sources, linear LDS dest) -> ds_read + convert + 24 MFMA on stage t ->
// one __syncthreads (vmcnt drain) per stage. In-flight tracking is structural.
__global__ __launch_bounds__(512, 4) void gemm_kernel(
    const float* __restrict__ X, const unsigned short* __restrict__ Whi,
    const unsigned short* __restrict__ Wlo, float* __restrict__ part)
{
    __shared__ float          sX[2][BMB * BK];    // 2 x 32 KB
    __shared__ unsigned short sH[2][NEXP * BK];   // 2 x 4 KB
    __shared__ unsigned short sL[2][NEXP * BK];   // 2 x 4 KB

    const int tid  = threadIdx.x;
    const int lane = tid & 63;
    const int w    = tid >> 6;                 // wave 0..7
    const int tb   = blockIdx.x >> 3;          // token block 0..63
    const int s    = blockIdx.x & 7;           // k-split    0..7
    const int kbase = s * KPER;
    const int tok0 = tb * BMB;

    // ---- X staging: per-lane pre-swizzled global sources, linear LDS dest ---
    // instr i of wave w covers LDS float seg [seg*256, +256), seg = i*8+w.
    // LDS[row*32 + c'] holds X[row][ (c' ^ swz(row)) ], swz = ((row&4)<<1)|((row&8)>>1)
    const float* xsrc[4];
    int xdst[4];
    #pragma unroll
    for (int i = 0; i < 4; ++i) {
        const int seg = i * 8 + w;
        const int o   = seg * 256 + lane * 4;
        const int row = o >> 5;
        const int cp  = o & 31;
        const int sw  = ((row & 4) << 1) | ((row & 8) >> 1);
        xsrc[i] = X + (size_t)(tok0 + row) * DDIM + kbase + (cp ^ sw);
        xdst[i] = seg * 256;                   // wave-uniform (depends on w,i)
    }
    // ---- W staging: waves 0-3 stage hi, waves 4-7 stage lo (4 KB each) ------
    // LDS[e*32 + kk] holds W[e][ kk ^ ((e&3)*8) ]
    const int wseg = w & 3;
    const int wo   = wseg * 512 + lane * 8;    // short offset in buffer
    const int we   = wo >> 5;
    const int wkk  = wo & 31;
    const unsigned short* wsrc =
        ((w < 4) ? Whi : Wlo) + (size_t)we * DDIM + kbase + (wkk ^ ((we & 3) * 8));

    // ---- prologue: stage 0 into buffer 0 ----
    #pragma unroll
    for (int i = 0; i < 4; ++i) gl2lds16(xsrc[i], &sX[0][xdst[i]]);
    gl2lds16(wsrc, (w < 4) ? (void*)&sH[0][wseg * 512] : (void*)&sL[0][wseg * 512]);
    __syncthreads();

    // ---- fragment read geometry ----
    const int fr = lane & 15;                  // token row / expert col in frag
    const int fg = lane >> 4;                  // k subgroup
    const int sw  = ((fr & 4) << 1) | ((fr & 8) >> 1);
    const int fo0 = (fg * 8) ^ sw;             // A slot, floats
    const int fo1 = (fg * 8 + 4) ^ sw;
    const int frow0 = (w * 32 + fr) * BK;      // float offsets
    const int frow1 = frow0 + 16 * BK;
    const int bt  = (fg * 8) ^ ((fr & 3) * 8); // B slot, shorts

    f32x4 acc[2][4];
    #pragma unroll
    for (int mg = 0; mg < 2; ++mg)
        #pragma unroll
        for (int ng = 0; ng < 4; ++ng)
            acc[mg][ng] = (f32x4){0.f, 0.f, 0.f, 0.f};

    for (int st = 0; st < NSTG; ++st) {
        const float*          cx = sX[st & 1];
        const unsigned short* ch = sH[st & 1];
        const unsigned short* cl = sL[st & 1];

        // ---- issue next stage's loads (land during this stage's compute) ----
        if (st + 1 < NSTG) {
            const int nb = (st + 1) & 1;
            #pragma unroll
            for (int i = 0; i < 4; ++i)
                gl2lds16(xsrc[i] + (st + 1) * BK, &sX[nb][xdst[i]]);
            gl2lds16(wsrc + (st + 1) * BK,
                     (w < 4) ? (void*)&sH[nb][wseg * 512]
                             : (void*)&sL[nb][wseg * 512]);
        }

        // ---- A fragments from LDS (swizzled b128 reads) ----
        const float4 a00 = *(const float4*)&cx[frow0 + fo0];
        const float4 a01 = *(const float4*)&cx[frow0 + fo1];
        const float4 a10 = *(const float4*)&cx[frow1 + fo0];
        const float4 a11 = *(const float4*)&cx[frow1 + fo1];

        // ---- RTZ split fp32 -> bf16 hi/lo ----
        short8 ahi[2], alo[2];
        #pragma unroll
        for (int mg = 0; mg < 2; ++mg) {
            const float4 qa = mg ? a10 : a00;
            const float4 qb = mg ? a11 : a01;
            unsigned int hi[4], lo[4];
            const unsigned int u0 = __float_as_uint(qa.x), u1 = __float_as_uint(qa.y);
            const unsigned int u2 = __float_as_uint(qa.z), u3 = __float_as_uint(qa.w);
            const unsigned int u4 = __float_as_uint(qb.x), u5 = __float_as_uint(qb.y);
            const unsigned int u6 = __float_as_uint(qb.z), u7 = __float_as_uint(qb.w);
            hi[0] = (u0 >> 16) | (u1 & 0xFFFF0000u);
            hi[1] = (u2 >> 16) | (u3 & 0xFFFF0000u);
            hi[2] = (u4 >> 16) | (u5 & 0xFFFF0000u);
            hi[3] = (u6 >> 16) | (u7 & 0xFFFF0000u);
            const float l0 = qa.x - __uint_as_float(u0 & 0xFFFF0000u);
            const float l1 = qa.y - __uint_as_float(u1 & 0xFFFF0000u);
            const float l2 = qa.z - __uint_as_float(u2 & 0xFFFF0000u);
            const float l3 = qa.w - __uint_as_float(u3 & 0xFFFF0000u);
            const float l4 = qb.x - __uint_as_float(u4 & 0xFFFF0000u);
            const float l5 = qb.y - __uint_as_float(u5 & 0xFFFF0000u);
            const float l6 = qb.z - __uint_as_float(u6 & 0xFFFF0000u);
            const float l7 = qb.w - __uint_as_float(u7 & 0xFFFF0000u);
            lo[0] = (__float_as_uint(l0) >> 16) | (__float_as_uint(l1) & 0xFFFF0000u);
            lo[1] = (__float_as_uint(l2) >> 16) | (__float_as_uint(l3) & 0xFFFF0000u);
            lo[2] = (__float_as_uint(l4) >> 16) | (__float_as_uint(l5) & 0xFFFF0000u);
            lo[3] = (__float_as_uint(l6) >> 16) | (__float_as_uint(l7) & 0xFFFF0000u);
            ahi[mg] = mk8(hi[0], hi[1], hi[2], hi[3]);
            alo[mg] = mk8(lo[0], lo[1], lo[2], lo[3]);
        }

        // ---- B fragments + 24 MFMAs ----
        #pragma unroll
        for (int ng = 0; ng < 4; ++ng) {
            const int bo = (ng * 16 + fr) * BK + bt;
            const short8 bh = *(const short8*)&ch[bo];
            const short8 bl = *(const short8*)&cl[bo];
            #pragma unroll
            for (int mg = 0; mg < 2; ++mg) {
                acc[mg][ng] = __builtin_amdgcn_mfma_f32_16x16x32_bf16(
                    ahi[mg], bh, acc[mg][ng], 0, 0, 0);
                acc[mg][ng] = __builtin_amdgcn_mfma_f32_16x16x32_bf16(
                    ahi[mg], bl, acc[mg][ng], 0, 0, 0);
                acc[mg][ng] = __builtin_amdgcn_mfma_f32_16x16x32_bf16(
                    alo[mg], bh, acc[mg][ng], 0, 0, 0);
            }
        }

        __syncthreads();   // drains vmcnt: buffer (st+1)&1 is ready
    }

    // ---- store partials [n][s][e] ----
    // C/D layout: col = lane&15 (expert), row = fg*4 + reg (token)
    #pragma unroll
    for (int mg = 0; mg < 2; ++mg)
        #pragma unroll
        for (int r = 0; r < 4; ++r) {
            const int row = tok0 + w * 32 + mg * 16 + fg * 4 + r;
            float* __restrict__ pp = part + ((size_t)row * SPLITK + s) * NEXP;
            #pragma unroll
            for (int ng = 0; ng < 4; ++ng)
                pp[ng * 16 + fr] = acc[mg][ng][r];
        }
}

// ---------------- Kernel 3: softmax + group-limited top-k routing ------------
__global__ __launch_bounds__(256) void route_kernel(
    const float* __restrict__ part, float* __restrict__ outW,
    float* __restrict__ outI, float* __restrict__ counts)
{
    __shared__ int hist[NEXP];
    const int tid = threadIdx.x;
    if (tid < NEXP) hist[tid] = 0;
    __syncthreads();

    const int lane = tid & 63;
    const int wv   = tid >> 6;   // wave 0..3
    const int tok_base = blockIdx.x * 32 + wv * 8;

    for (int t = 0; t < 8; ++t) {
        const int n = tok_base + t;
        // sum split-K partials (layout [n][s][e]): 2 KB contiguous per token
        float L = 0.0f;
        #pragma unroll
        for (int s = 0; s < SPLITK; ++s)
            L += part[((size_t)n * SPLITK + s) * NEXP + lane];

        // softmax over 64 experts (wave = expert axis)
        float m = L;
        #pragma unroll
        for (int off = 32; off > 0; off >>= 1) m = fmaxf(m, __shfl_xor(m, off));
        float p = expf(L - m);
        float ssum = p;
        #pragma unroll
        for (int off = 32; off > 0; off >>= 1) ssum += __shfl_xor(ssum, off);
        float score = p / ssum;

        // group max within each 8-lane group
        float gm = score;
        gm = fmaxf(gm, __shfl_xor(gm, 1));
        gm = fmaxf(gm, __shfl_xor(gm, 2));
        gm = fmaxf(gm, __shfl_xor(gm, 4));

        // gather all 8 group maxima, serial top-4 groups (ties -> lower index)
        float ga[8];
        #pragma unroll
        for (int g = 0; g < 8; ++g) ga[g] = __shfl(gm, g * 8);
        unsigned selmask = 0u;
        #pragma unroll
        for (int r = 0; r < 4; ++r) {
            float best = -INFINITY; int bg = 0;
            #pragma unroll
            for (int g = 0; g < 8; ++g) {
                bool taken  = (selmask >> g) & 1u;
                bool better = (!taken) && (ga[g] > best);
                bg   = better ? g : bg;
                best = better ? ga[g] : best;
            }
            selmask |= (1u << bg);
        }

        // mask non-selected groups, wave-wide top-4 (ties -> lower idx)
        float ms = ((selmask >> (lane >> 3)) & 1u) ? score : -INFINITY;
        float wk[4]; int wi[4];
        #pragma unroll
        for (int r = 0; r < 4; ++r) {
            float v = ms; int ix = lane;
            #pragma unroll
            for (int off = 32; off > 0; off >>= 1) {
                float vo = __shfl_xor(v, off);
                int   io = __shfl_xor(ix, off);
                if (vo > v || (vo == v && io < ix)) { v = vo; ix = io; }
            }
            wk[r] = v; wi[r] = ix;
            if (lane == ix) ms = -INFINITY;
        }

        if (lane == 0) {
            *(float4*)&outW[(size_t)n * 4] = make_float4(wk[0], wk[1], wk[2], wk[3]);
            *(float4*)&outI[(size_t)n * 4] =
                make_float4((float)wi[0], (float)wi[1], (float)wi[2], (float)wi[3]);
            atomicAdd(&hist[wi[0]], 1);
            atomicAdd(&hist[wi[1]], 1);
            atomicAdd(&hist[wi[2]], 1);
            atomicAdd(&hist[wi[3]], 1);
        }
    }

    __syncthreads();
    if (tid < NEXP) atomicAdd(&counts[tid], (float)hist[tid]);
}

extern "C" void kernel_launch(void* const* d_in, const int* in_sizes, int n_in,
                              void* d_out, int out_size, void* d_ws, size_t ws_size,
                              hipStream_t stream) {
    const float* X = (const float*)d_in[0];
    const float* W = (const float*)d_in[1];

    float* outW   = (float*)d_out;                    // [N,4] weights
    float* outI   = outW + (size_t)NTOK * KTOP;       // [N,4] indices (as float)
    float* counts = outW + (size_t)2 * NTOK * KTOP;   // [64]  counts  (as float)

    float*          part = (float*)d_ws;                              // 32 MB
    unsigned short* Whi  = (unsigned short*)(part + (size_t)NTOK * SPLITK * NEXP);
    unsigned short* Wlo  = Whi + (size_t)NEXP * DDIM;

    prep_kernel<<<(NEXP * DDIM) / 256, 256, 0, stream>>>(W, Whi, Wlo, counts);
    gemm_kernel<<<(NTOK / BMB) * SPLITK, 512, 0, stream>>>(X, Whi, Wlo, part);
    route_kernel<<<NTOK / 32, 256, 0, stream>>>(part, outW, outI, counts);
}